// Round 20
// baseline (60.563 us; speedup 1.0000x reference)
//
#include <hip/hip_runtime.h>
#include <math.h>

namespace {

constexpr int B = 2048;
constexpr int C = 20000;
constexpr int D = 512;
constexpr int LMAX = 8;

constexpr int BMt = 128, BNt = 128;          // GEMM block tile
constexpr int NROWT = B / BMt;               // 16 row tiles
constexpr int NPAN  = (C + BNt - 1) / BNt;   // 157 col panels (last: 32 valid)
constexpr int KST   = D / 64;                // 8 K-steps
constexpr int SLOTS = 512;                   // 16B slots per (tile,kstep)
constexpr int NWG   = NROWT * NPAN;          // 2512 (divisible by 8 XCDs)
constexpr int NBLK_F = B / 32;               // 64 fused norm+pack blocks for f
constexpr int NBLK_W = C / 32;               // 625 for w
constexpr int NBLK_PAD = 3;                  // zero-fill pad rows 20000..20095

constexpr float S_SCALE = 30.0f;
constexpr float COS_M = 0.87758256189037271f;   // cos(0.5)
constexpr float SIN_M = 0.47942553860420301f;   // sin(0.5)
constexpr float TH    = -0.87758256189037271f;  // cos(pi - 0.5)
constexpr float MM    = 0.23971276930210156f;   // sin(pi - 0.5) * 0.5
constexpr float MFIX  = 30.0f;                  // fixed softmax shift: |logits| <= 30

typedef float f32x16 __attribute__((ext_vector_type(16)));
typedef int   i32x8  __attribute__((ext_vector_type(8)));

union FragU { ulonglong2 u2[2]; i32x8 v; };

// MX-scaled fp8 MFMA, K=64, unit scales (E8M0 127 -> 2^0). With identical
// k-permutations on both operands the result equals the plain dot product.
// Transposed: first operand = our B (cols) -> D cols (lane&31) = logit ROWS.
__device__ __forceinline__ void mfma_mx_t(f32x16& acc, i32x8 bfrag, i32x8 afrag) {
    acc = __builtin_amdgcn_mfma_scale_f32_32x32x64_f8f6f4(
        bfrag, afrag, acc, 0 /*cbsz: fp8*/, 0 /*blgp: fp8*/,
        0, 0x7F7F7F7F, 0, 0x7F7F7F7F);
}

// async global->LDS, 16B per lane; LDS dest = uniform base + lane*16 (HW).
__device__ __forceinline__ void gload_lds16(const ulonglong2* gsrc_lane, ulonglong2* lds_base) {
    __builtin_amdgcn_global_load_lds(
        (const __attribute__((address_space(1))) unsigned int*)gsrc_lane,
        (__attribute__((address_space(3))) unsigned int*)lds_base,
        16, 0, 0);
}

// 8 fp32 -> 8 fp8 e4m3 bytes (hardware RNE pack), element j = byte j
__device__ __forceinline__ unsigned long long pack8_fp8(const float* xs, float sc) {
    int d0 = __builtin_amdgcn_cvt_pk_fp8_f32(xs[0] * sc, xs[1] * sc, 0, false);
    d0 = __builtin_amdgcn_cvt_pk_fp8_f32(xs[2] * sc, xs[3] * sc, d0, true);
    int d1 = __builtin_amdgcn_cvt_pk_fp8_f32(xs[4] * sc, xs[5] * sc, 0, false);
    d1 = __builtin_amdgcn_cvt_pk_fp8_f32(xs[6] * sc, xs[7] * sc, d1, true);
    return (unsigned long long)(unsigned)d0 | ((unsigned long long)(unsigned)d1 << 32);
}

__device__ __forceinline__ float wave_sum(float v) {
    #pragma unroll
    for (int off = 1; off < 64; off <<= 1) v += __shfl_xor(v, off, 64);
    return v;
}

// Fused norm+pack (proven R18): one block = 32 rows = one m_frag slot-group.
__global__ void pack_norm_kernel(const float* __restrict__ f, const float* __restrict__ w,
                                 float* __restrict__ fn, float* __restrict__ wn,
                                 ulonglong2* __restrict__ Ap, ulonglong2* __restrict__ Bp) {
    __shared__ float sInv[32];
    const int id = blockIdx.x;
    const int t = threadIdx.x, lane = t & 63, wv = t >> 6;

    if (id >= NBLK_F + NBLK_W) {                // pad-zero blocks
        const int g = id - (NBLK_F + NBLK_W);   // 0..2 -> mfr 1..3 of tile 156
        #pragma unroll
        for (int i = 0; i < 4; ++i) {
            const int v = i * 256 + t;          // 0..1023
            const int s = v >> 7, u = v & 127;
            const int k32 = u >> 6, l = u & 63;
            Bp[(size_t)((NPAN - 1) * KST + s) * SLOTS + ((g + 1) * 2 + k32) * 64 + l]
                = make_ulonglong2(0ull, 0ull);
        }
        return;
    }

    const bool isA = id < NBLK_F;
    const int r0 = (isA ? id : id - NBLK_F) * 32;       // first row of group
    const float* src = isA ? f : w;
    float* nrm_out = isA ? fn : wn;
    const int tile = r0 >> 7;                  // /128
    const int mfr = (r0 >> 5) & 3;             // (r0%128)/32
    ulonglong2* base = (isA ? Ap : Bp) + (size_t)(tile * KST) * SLOTS;

    #pragma unroll
    for (int rr = 0; rr < 8; ++rr) {
        const int lr = wv * 8 + rr;
        const int row = r0 + lr;
        const float4* p = reinterpret_cast<const float4*>(src + (size_t)row * D);
        const float4 a = p[lane * 2 + 0];
        const float4 b = p[lane * 2 + 1];
        float s2 = a.x*a.x + a.y*a.y + a.z*a.z + a.w*a.w
                 + b.x*b.x + b.y*b.y + b.z*b.z + b.w*b.w;
        s2 = wave_sum(s2);
        if (lane == 0) {
            const float nrm = sqrtf(s2);
            nrm_out[row] = nrm;
            sInv[lr] = 1.0f / fmaxf(nrm, 1e-8f);
        }
    }
    __syncthreads();

    #pragma unroll
    for (int i = 0; i < 4; ++i) {
        const int v = i * 256 + t;             // 0..1023
        const int s = v >> 7, u = v & 127;
        const int k32 = u >> 6, l = u & 63;
        const int lr = l & 31;
        const int row = r0 + lr;
        const int kb = s * 64 + k32 * 32 + ((l >> 5) << 3);
        const float sc = sInv[lr];
        float xs[8];
        *reinterpret_cast<float4*>(&xs[0]) = *reinterpret_cast<const float4*>(&src[(size_t)row * D + kb]);
        *reinterpret_cast<float4*>(&xs[4]) = *reinterpret_cast<const float4*>(&src[(size_t)row * D + kb + 4]);
        const unsigned long long lo = pack8_fp8(xs, sc);
        *reinterpret_cast<float4*>(&xs[0]) = *reinterpret_cast<const float4*>(&src[(size_t)row * D + kb + 16]);
        *reinterpret_cast<float4*>(&xs[4]) = *reinterpret_cast<const float4*>(&src[(size_t)row * D + kb + 20]);
        const unsigned long long hi = pack8_fp8(xs, sc);
        base[(size_t)s * SLOTS + (mfr * 2 + k32) * 64 + l] = make_ulonglong2(lo, hi);
    }
}

// MX-FP8 MFMA GEMM, 3-buffer rotation + REGISTER-PIPELINED fragment reads:
// at iteration s, issue ds_reads for step s+1 right after the barrier, then
// run MFMAs of step s from registers read last iteration -> LDS-read latency
// hides under MFMA + STAGE + vmcnt of the surrounding iterations (de-convoy).
// lgkmcnt(0) before each barrier guarantees reads of buf[s%3] complete before
// its overwrite (issued post-barrier, lands >= L2 latency later).
// Counted vmcnt(4), never 0 mid-loop. Transposed acc: lane&31 = logit ROW.
// pZ[row][panel] = sum_cols exp(30*cos - 30).
__global__ __launch_bounds__(256, 3) void
gemm_mfma_kernel(const ulonglong2* __restrict__ Ap, const ulonglong2* __restrict__ Bp,
                 float* __restrict__ pZ)
{
    __shared__ ulonglong2 sBuf[3][1024];   // [buf][A:0..511 | B:512..1023] = 48KB
    __shared__ float sRed[BMt][2];
    const int wgid = blockIdx.x;
    const int swz = (wgid & 7) * (NWG / 8) + (wgid >> 3);   // bijective (NWG%8==0)
    const int bx = swz & 15;          // row tile
    const int by = swz >> 4;          // panel
    const int tid  = threadIdx.x;
    const int lane = tid & 63;
    const int half = lane >> 5, l31 = lane & 31;
    const int w    = tid >> 6;
    const int wm   = w >> 1;          // 0..1: rows wm*64
    const int wnn  = w & 1;           // 0..1: cols wnn*64

    const ulonglong2* Ab = Ap + (size_t)bx * KST * SLOTS;
    const ulonglong2* Bb = Bp + (size_t)by * KST * SLOTS;

    auto STAGE = [&](int bufIdx, int s) {
        const ulonglong2* As = Ab + (size_t)s * SLOTS;
        const ulonglong2* Bs = Bb + (size_t)s * SLOTS;
        #pragma unroll
        for (int i = 0; i < 4; ++i) {
            const int g = w * 4 + i;                 // 0..15
            const int off = (g & 7) * 64;
            const ulonglong2* src = (g < 8) ? (As + off + lane) : (Bs + off + lane);
            ulonglong2* dst = &sBuf[bufIdx][(g < 8 ? 0 : 512) + off];
            gload_lds16(src, dst);
        }
    };

    auto READF = [&](int bufIdx, FragU& a0u, FragU& a1u, FragU& b0u, FragU& b1u) {
        const ulonglong2* Abuf = &sBuf[bufIdx][0];
        const ulonglong2* Bbuf = &sBuf[bufIdx][512];
        a0u.u2[0] = Abuf[((wm * 2 + 0) * 2 + 0) * 64 + lane];   // m0,k32=0
        a0u.u2[1] = Abuf[((wm * 2 + 0) * 2 + 1) * 64 + lane];   // m0,k32=1
        a1u.u2[0] = Abuf[((wm * 2 + 1) * 2 + 0) * 64 + lane];   // m1,k32=0
        a1u.u2[1] = Abuf[((wm * 2 + 1) * 2 + 1) * 64 + lane];   // m1,k32=1
        b0u.u2[0] = Bbuf[((wnn * 2 + 0) * 2 + 0) * 64 + lane];
        b0u.u2[1] = Bbuf[((wnn * 2 + 0) * 2 + 1) * 64 + lane];
        b1u.u2[0] = Bbuf[((wnn * 2 + 1) * 2 + 0) * 64 + lane];
        b1u.u2[1] = Bbuf[((wnn * 2 + 1) * 2 + 1) * 64 + lane];
    };

    f32x16 accT00, accT01, accT10, accT11;   // cols(lane&31)=logit rows
    #pragma unroll
    for (int i = 0; i < 16; ++i) { accT00[i] = 0.f; accT01[i] = 0.f; accT10[i] = 0.f; accT11[i] = 0.f; }

    STAGE(0, 0);
    STAGE(1, 1);
    asm volatile("s_waitcnt vmcnt(4)" ::: "memory");   // stage(0) done
    __builtin_amdgcn_s_barrier();

    FragU ca0, ca1, cb0, cb1;
    READF(0, ca0, ca1, cb0, cb1);                       // frags(0)

    #pragma unroll
    for (int s = 0; s < KST; ++s) {
        if (s + 2 < KST) STAGE((s + 2) % 3, s + 2);     // overwrite buf read at s-1
        FragU na0, na1, nb0, nb1;
        if (s + 1 < KST) {
            if (s + 2 < KST) {
                asm volatile("s_waitcnt vmcnt(4)" ::: "memory");   // stage(s+1) done
            } else {
                asm volatile("s_waitcnt vmcnt(0)" ::: "memory");   // last stage: drain
            }
            asm volatile("s_waitcnt lgkmcnt(0)" ::: "memory");     // my reads(s) done
            __builtin_amdgcn_s_barrier();
            READF((s + 1) % 3, na0, na1, nb0, nb1);     // issue reads(s+1)
        }
        __builtin_amdgcn_s_setprio(1);                  // MFMAs of step s (regs)
        mfma_mx_t(accT00, cb0.v, ca0.v);
        mfma_mx_t(accT01, cb0.v, ca1.v);
        mfma_mx_t(accT10, cb1.v, ca0.v);
        mfma_mx_t(accT11, cb1.v, ca1.v);
        __builtin_amdgcn_s_setprio(0);
        if (s + 1 < KST) { ca0 = na0; ca1 = na1; cb0 = nb0; cb1 = nb1; }
    }

    // ---- epilogue: per-lane row partials, single cross-lane step ----
    float zA = 0.0f;   // row = wm*64 + l31
    float zB = 0.0f;   // row = wm*64 + 32 + l31
    const int cbase = by * BNt + wnn * 64 + 4 * half;
    #pragma unroll
    for (int r = 0; r < 16; ++r) {
        const int cb = cbase + (r & 3) + 8 * (r >> 2);
        const float eA0 = (cb      < C) ? __expf(fmaf(accT00[r], S_SCALE, -MFIX)) : 0.0f;
        const float eB0 = (cb      < C) ? __expf(fmaf(accT01[r], S_SCALE, -MFIX)) : 0.0f;
        const float eA1 = (cb + 32 < C) ? __expf(fmaf(accT10[r], S_SCALE, -MFIX)) : 0.0f;
        const float eB1 = (cb + 32 < C) ? __expf(fmaf(accT11[r], S_SCALE, -MFIX)) : 0.0f;
        zA += eA0 + eA1;
        zB += eB0 + eB1;
    }
    zA += __shfl_xor(zA, 32, 64);    // combine the two col-halves of each row
    zB += __shfl_xor(zB, 32, 64);
    if (half == 0) {
        sRed[wm * 64 + l31][wnn]      = zA;
        sRed[wm * 64 + 32 + l31][wnn] = zB;
    }
    __syncthreads();
    if (tid < BMt) {
        pZ[(size_t)(bx * BMt + tid) * NPAN + by] = sRed[tid][0] + sRed[tid][1];
    }
}

// One wave per row: sum NPAN partials (fixed shift M=30), exact fp32 target
// logits + ArcFace margin, correct Z, emit per-row loss.
__global__ void finalize_kernel(const float* __restrict__ f, const float* __restrict__ w,
                                const float* __restrict__ fn, const float* __restrict__ wn,
                                const int* __restrict__ pinds, const int* __restrict__ lengths,
                                const float* __restrict__ pZ, float* __restrict__ loss)
{
    const int b = blockIdx.x;
    const int lane = threadIdx.x;

    float Zp = 0.0f;
    for (int p = lane; p < NPAN; p += 64) Zp += pZ[(size_t)b * NPAN + p];
    Zp = wave_sum(Zp);

    const float4* fp = reinterpret_cast<const float4*>(f + (size_t)b * D);
    const float4 a0 = fp[lane * 2 + 0];
    const float4 a1 = fp[lane * 2 + 1];
    const float fnb = fn[b];
    const int len = lengths[b];

    float opl[LMAX], ops[LMAX];
    int cs[LMAX];
    #pragma unroll
    for (int j = 0; j < LMAX; ++j) {
        const int c = pinds[(size_t)b * LMAX + j];
        cs[j] = c;
        const float4* wp = reinterpret_cast<const float4*>(w + (size_t)c * D);
        const float4 w0 = wp[lane * 2 + 0];
        const float4 w1 = wp[lane * 2 + 1];
        float d = a0.x*w0.x + a0.y*w0.y + a0.z*w0.z + a0.w*w0.w
                + a1.x*w1.x + a1.y*w1.y + a1.z*w1.z + a1.w*w1.w;
        d = wave_sum(d);
        const float cosv = d / fmaxf(fnb * wn[c], 1e-8f);
        const float sine = sqrtf(fminf(fmaxf(1.0f - cosv * cosv, 0.0f), 1.0f));
        float phi = cosv * COS_M - sine * SIN_M;
        phi = (cosv > TH) ? phi : (cosv - MM);
        opl[j] = S_SCALE * cosv;
        ops[j] = S_SCALE * phi;
    }

    // correct Z for unique positive classes (margin applied), then ragged CE
    float Zc = Zp;
    for (int j = 0; j < len; ++j) {
        bool dup = false;
        for (int jj = 0; jj < j; ++jj) dup = dup || (cs[jj] == cs[j]);
        if (!dup) Zc += expf(ops[j] - MFIX) - expf(opl[j] - MFIX);
    }
    const float lZ = logf(Zc);
    float acc = 0.0f;
    for (int j = 0; j < len; ++j) acc += (MFIX + lZ - ops[j]);
    const float Lf = (float)len;
    if (lane == 0) loss[b] = acc / (Lf * Lf);
}

__global__ void reduce_kernel(const float* __restrict__ loss, float* __restrict__ out) {
    __shared__ float sdata[256];
    const int t = threadIdx.x;
    float s = 0.0f;
    for (int i = t; i < B; i += 256) s += loss[i];
    sdata[t] = s;
    __syncthreads();
    for (int off = 128; off > 0; off >>= 1) {
        if (t < off) sdata[t] += sdata[t + off];
        __syncthreads();
    }
    if (t == 0) out[0] = sdata[0] * (1.0f / (float)B);
}

} // anonymous namespace

extern "C" void kernel_launch(void* const* d_in, const int* in_sizes, int n_in,
                              void* d_out, int out_size, void* d_ws, size_t ws_size,
                              hipStream_t stream) {
    const float* f   = (const float*)d_in[0];
    // d_in[1] = labels [B,C] — not needed (reconstructed from pinds/lengths)
    const float* w   = (const float*)d_in[2];
    const int* pinds = (const int*)d_in[3];
    const int* lens  = (const int*)d_in[4];
    float* out = (float*)d_out;

    char* ws = (char*)d_ws;
    size_t off = 0;
    auto alloc = [&](size_t bytes) { void* p = ws + off; off = (off + bytes + 255) & ~(size_t)255; return p; };

    float* wn   = (float*)alloc(C * 4);
    float* fn   = (float*)alloc(B * 4);
    float* pZ   = (float*)alloc((size_t)B * NPAN * 4);
    float* loss = (float*)alloc(B * 4);
    ulonglong2* Ap = (ulonglong2*)alloc((size_t)NROWT * KST * SLOTS * 16);
    ulonglong2* Bp = (ulonglong2*)alloc((size_t)NPAN  * KST * SLOTS * 16);

    pack_norm_kernel<<<dim3(NBLK_F + NBLK_W + NBLK_PAD), 256, 0, stream>>>(f, w, fn, wn, Ap, Bp);
    gemm_mfma_kernel<<<dim3(NWG), 256, 0, stream>>>(Ap, Bp, pZ);
    finalize_kernel<<<dim3(B), 64, 0, stream>>>(f, w, fn, wn, pinds, lens, pZ, loss);
    reduce_kernel<<<dim3(1), 256, 0, stream>>>(loss, out);
}

// Round 21
// 59.137 us; speedup vs baseline: 1.0241x; 1.0241x over previous
//
#include <hip/hip_runtime.h>
#include <math.h>

namespace {

constexpr int B = 2048;
constexpr int C = 20000;
constexpr int D = 512;
constexpr int LMAX = 8;

constexpr int BMt = 128, BNt = 128;          // GEMM block tile
constexpr int NROWT = B / BMt;               // 16 row tiles
constexpr int NPAN  = (C + BNt - 1) / BNt;   // 157 col panels (last: 32 valid)
constexpr int KST   = D / 64;                // 8 K-steps
constexpr int SLOTS = 512;                   // 16B slots per (tile,kstep)
constexpr int NWG   = NROWT * NPAN;          // 2512 (divisible by 8 XCDs)
constexpr int NBLK_F = B / 32;               // 64 fused norm+pack blocks for f
constexpr int NBLK_W = C / 32;               // 625 for w
constexpr int NBLK_PAD = 3;                  // zero-fill pad rows 20000..20095

constexpr float S_SCALE = 30.0f;
constexpr float COS_M = 0.87758256189037271f;   // cos(0.5)
constexpr float SIN_M = 0.47942553860420301f;   // sin(0.5)
constexpr float TH    = -0.87758256189037271f;  // cos(pi - 0.5)
constexpr float MM    = 0.23971276930210156f;   // sin(pi - 0.5) * 0.5
constexpr float MFIX  = 30.0f;                  // fixed softmax shift: |logits| <= 30

typedef float f32x16 __attribute__((ext_vector_type(16)));
typedef int   i32x8  __attribute__((ext_vector_type(8)));

union FragU { ulonglong2 u2[2]; i32x8 v; };

// MX-scaled fp8 MFMA, K=64, unit scales (E8M0 127 -> 2^0). With identical
// k-permutations on both operands the result equals the plain dot product.
// Transposed: first operand = our B (cols) -> D cols (lane&31) = logit ROWS.
__device__ __forceinline__ void mfma_mx_t(f32x16& acc, i32x8 bfrag, i32x8 afrag) {
    acc = __builtin_amdgcn_mfma_scale_f32_32x32x64_f8f6f4(
        bfrag, afrag, acc, 0 /*cbsz: fp8*/, 0 /*blgp: fp8*/,
        0, 0x7F7F7F7F, 0, 0x7F7F7F7F);
}

// async global->LDS, 16B per lane; LDS dest = uniform base + lane*16 (HW).
__device__ __forceinline__ void gload_lds16(const ulonglong2* gsrc_lane, ulonglong2* lds_base) {
    __builtin_amdgcn_global_load_lds(
        (const __attribute__((address_space(1))) unsigned int*)gsrc_lane,
        (__attribute__((address_space(3))) unsigned int*)lds_base,
        16, 0, 0);
}

// 8 fp32 -> 8 fp8 e4m3 bytes (hardware RNE pack), element j = byte j
__device__ __forceinline__ unsigned long long pack8_fp8(const float* xs, float sc) {
    int d0 = __builtin_amdgcn_cvt_pk_fp8_f32(xs[0] * sc, xs[1] * sc, 0, false);
    d0 = __builtin_amdgcn_cvt_pk_fp8_f32(xs[2] * sc, xs[3] * sc, d0, true);
    int d1 = __builtin_amdgcn_cvt_pk_fp8_f32(xs[4] * sc, xs[5] * sc, 0, false);
    d1 = __builtin_amdgcn_cvt_pk_fp8_f32(xs[6] * sc, xs[7] * sc, d1, true);
    return (unsigned long long)(unsigned)d0 | ((unsigned long long)(unsigned)d1 << 32);
}

__device__ __forceinline__ float wave_sum(float v) {
    #pragma unroll
    for (int off = 1; off < 64; off <<= 1) v += __shfl_xor(v, off, 64);
    return v;
}

// Fused norm+pack (proven R18): one block = 32 rows = one m_frag slot-group.
__global__ void pack_norm_kernel(const float* __restrict__ f, const float* __restrict__ w,
                                 float* __restrict__ fn, float* __restrict__ wn,
                                 ulonglong2* __restrict__ Ap, ulonglong2* __restrict__ Bp) {
    __shared__ float sInv[32];
    const int id = blockIdx.x;
    const int t = threadIdx.x, lane = t & 63, wv = t >> 6;

    if (id >= NBLK_F + NBLK_W) {                // pad-zero blocks
        const int g = id - (NBLK_F + NBLK_W);   // 0..2 -> mfr 1..3 of tile 156
        #pragma unroll
        for (int i = 0; i < 4; ++i) {
            const int v = i * 256 + t;          // 0..1023
            const int s = v >> 7, u = v & 127;
            const int k32 = u >> 6, l = u & 63;
            Bp[(size_t)((NPAN - 1) * KST + s) * SLOTS + ((g + 1) * 2 + k32) * 64 + l]
                = make_ulonglong2(0ull, 0ull);
        }
        return;
    }

    const bool isA = id < NBLK_F;
    const int r0 = (isA ? id : id - NBLK_F) * 32;       // first row of group
    const float* src = isA ? f : w;
    float* nrm_out = isA ? fn : wn;
    const int tile = r0 >> 7;                  // /128
    const int mfr = (r0 >> 5) & 3;             // (r0%128)/32
    ulonglong2* base = (isA ? Ap : Bp) + (size_t)(tile * KST) * SLOTS;

    #pragma unroll
    for (int rr = 0; rr < 8; ++rr) {
        const int lr = wv * 8 + rr;
        const int row = r0 + lr;
        const float4* p = reinterpret_cast<const float4*>(src + (size_t)row * D);
        const float4 a = p[lane * 2 + 0];
        const float4 b = p[lane * 2 + 1];
        float s2 = a.x*a.x + a.y*a.y + a.z*a.z + a.w*a.w
                 + b.x*b.x + b.y*b.y + b.z*b.z + b.w*b.w;
        s2 = wave_sum(s2);
        if (lane == 0) {
            const float nrm = sqrtf(s2);
            nrm_out[row] = nrm;
            sInv[lr] = 1.0f / fmaxf(nrm, 1e-8f);
        }
    }
    __syncthreads();

    #pragma unroll
    for (int i = 0; i < 4; ++i) {
        const int v = i * 256 + t;             // 0..1023
        const int s = v >> 7, u = v & 127;
        const int k32 = u >> 6, l = u & 63;
        const int lr = l & 31;
        const int row = r0 + lr;
        const int kb = s * 64 + k32 * 32 + ((l >> 5) << 3);
        const float sc = sInv[lr];
        float xs[8];
        *reinterpret_cast<float4*>(&xs[0]) = *reinterpret_cast<const float4*>(&src[(size_t)row * D + kb]);
        *reinterpret_cast<float4*>(&xs[4]) = *reinterpret_cast<const float4*>(&src[(size_t)row * D + kb + 4]);
        const unsigned long long lo = pack8_fp8(xs, sc);
        *reinterpret_cast<float4*>(&xs[0]) = *reinterpret_cast<const float4*>(&src[(size_t)row * D + kb + 16]);
        *reinterpret_cast<float4*>(&xs[4]) = *reinterpret_cast<const float4*>(&src[(size_t)row * D + kb + 20]);
        const unsigned long long hi = pack8_fp8(xs, sc);
        base[(size_t)s * SLOTS + (mfr * 2 + k32) * 64 + l] = make_ulonglong2(lo, hi);
    }
}

// MX-FP8 MFMA GEMM, 2-buffer double-buffer (R16-proven sync) at 4 blocks/CU:
// LDS 33KB (fits 4), launch_bounds(256,4) caps VGPR at 128 (~116 used).
// 16 waves/CU hide LDS/stage latency. Counted vmcnt(4), never 0 mid-loop.
// Transposed accumulate: lane&31 owns one logit ROW.
// pZ[row][panel] = sum_cols exp(30*cos - 30).
__global__ __launch_bounds__(256, 4) void
gemm_mfma_kernel(const ulonglong2* __restrict__ Ap, const ulonglong2* __restrict__ Bp,
                 float* __restrict__ pZ)
{
    __shared__ ulonglong2 sBuf[2][1024];   // [buf][A:0..511 | B:512..1023] = 32KB
    __shared__ float sRed[BMt][2];
    const int wgid = blockIdx.x;
    const int swz = (wgid & 7) * (NWG / 8) + (wgid >> 3);   // bijective (NWG%8==0)
    const int bx = swz & 15;          // row tile
    const int by = swz >> 4;          // panel
    const int tid  = threadIdx.x;
    const int lane = tid & 63;
    const int half = lane >> 5, l31 = lane & 31;
    const int w    = tid >> 6;
    const int wm   = w >> 1;          // 0..1: rows wm*64
    const int wnn  = w & 1;           // 0..1: cols wnn*64

    const ulonglong2* Ab = Ap + (size_t)bx * KST * SLOTS;
    const ulonglong2* Bb = Bp + (size_t)by * KST * SLOTS;

    auto STAGE = [&](int bufIdx, int s) {
        const ulonglong2* As = Ab + (size_t)s * SLOTS;
        const ulonglong2* Bs = Bb + (size_t)s * SLOTS;
        #pragma unroll
        for (int i = 0; i < 4; ++i) {
            const int g = w * 4 + i;                 // 0..15
            const int off = (g & 7) * 64;
            const ulonglong2* src = (g < 8) ? (As + off + lane) : (Bs + off + lane);
            ulonglong2* dst = &sBuf[bufIdx][(g < 8 ? 0 : 512) + off];
            gload_lds16(src, dst);
        }
    };

    f32x16 accT00, accT01, accT10, accT11;   // cols(lane&31)=logit rows
    #pragma unroll
    for (int i = 0; i < 16; ++i) { accT00[i] = 0.f; accT01[i] = 0.f; accT10[i] = 0.f; accT11[i] = 0.f; }

    STAGE(0, 0);
    STAGE(1, 1);
    asm volatile("s_waitcnt vmcnt(4)" ::: "memory");   // buf0's 4 (per wave) done
    __builtin_amdgcn_s_barrier();

    #pragma unroll
    for (int s = 0; s < KST; ++s) {
        const int cur = s & 1;
        const ulonglong2* Abuf = &sBuf[cur][0];
        const ulonglong2* Bbuf = &sBuf[cur][512];
        FragU a0u, a1u, b0u, b1u;
        a0u.u2[0] = Abuf[((wm * 2 + 0) * 2 + 0) * 64 + lane];   // m0,k32=0
        a0u.u2[1] = Abuf[((wm * 2 + 0) * 2 + 1) * 64 + lane];   // m0,k32=1
        a1u.u2[0] = Abuf[((wm * 2 + 1) * 2 + 0) * 64 + lane];   // m1,k32=0
        a1u.u2[1] = Abuf[((wm * 2 + 1) * 2 + 1) * 64 + lane];   // m1,k32=1
        b0u.u2[0] = Bbuf[((wnn * 2 + 0) * 2 + 0) * 64 + lane];
        b0u.u2[1] = Bbuf[((wnn * 2 + 0) * 2 + 1) * 64 + lane];
        b1u.u2[0] = Bbuf[((wnn * 2 + 1) * 2 + 0) * 64 + lane];
        b1u.u2[1] = Bbuf[((wnn * 2 + 1) * 2 + 1) * 64 + lane];
        __builtin_amdgcn_s_setprio(1);
        mfma_mx_t(accT00, b0u.v, a0u.v);
        mfma_mx_t(accT01, b0u.v, a1u.v);
        mfma_mx_t(accT10, b1u.v, a0u.v);
        mfma_mx_t(accT11, b1u.v, a1u.v);
        __builtin_amdgcn_s_setprio(0);
        __builtin_amdgcn_s_barrier();                  // barA: all done reading buf[cur]
        if (s + 2 < KST) STAGE(cur, s + 2);            // overwrite cur with s+2
        if (s + 1 < KST) {
            if (s + 2 < KST) {
                asm volatile("s_waitcnt vmcnt(4)" ::: "memory");   // s+1's stage done
            } else {
                asm volatile("s_waitcnt vmcnt(0)" ::: "memory");   // last: drain
            }
            __builtin_amdgcn_s_barrier();              // barB: everyone's s+1 visible
        }
    }

    // ---- epilogue: per-lane row partials, single cross-lane step ----
    float zA = 0.0f;   // row = wm*64 + l31
    float zB = 0.0f;   // row = wm*64 + 32 + l31
    const int cbase = by * BNt + wnn * 64 + 4 * half;
    #pragma unroll
    for (int r = 0; r < 16; ++r) {
        const int cb = cbase + (r & 3) + 8 * (r >> 2);
        const float eA0 = (cb      < C) ? __expf(fmaf(accT00[r], S_SCALE, -MFIX)) : 0.0f;
        const float eB0 = (cb      < C) ? __expf(fmaf(accT01[r], S_SCALE, -MFIX)) : 0.0f;
        const float eA1 = (cb + 32 < C) ? __expf(fmaf(accT10[r], S_SCALE, -MFIX)) : 0.0f;
        const float eB1 = (cb + 32 < C) ? __expf(fmaf(accT11[r], S_SCALE, -MFIX)) : 0.0f;
        zA += eA0 + eA1;
        zB += eB0 + eB1;
    }
    zA += __shfl_xor(zA, 32, 64);    // combine the two col-halves of each row
    zB += __shfl_xor(zB, 32, 64);
    if (half == 0) {
        sRed[wm * 64 + l31][wnn]      = zA;
        sRed[wm * 64 + 32 + l31][wnn] = zB;
    }
    __syncthreads();
    if (tid < BMt) {
        pZ[(size_t)(bx * BMt + tid) * NPAN + by] = sRed[tid][0] + sRed[tid][1];
    }
}

// One wave per row: sum NPAN partials (fixed shift M=30), exact fp32 target
// logits + ArcFace margin, correct Z, emit per-row loss.
__global__ void finalize_kernel(const float* __restrict__ f, const float* __restrict__ w,
                                const float* __restrict__ fn, const float* __restrict__ wn,
                                const int* __restrict__ pinds, const int* __restrict__ lengths,
                                const float* __restrict__ pZ, float* __restrict__ loss)
{
    const int b = blockIdx.x;
    const int lane = threadIdx.x;

    float Zp = 0.0f;
    for (int p = lane; p < NPAN; p += 64) Zp += pZ[(size_t)b * NPAN + p];
    Zp = wave_sum(Zp);

    const float4* fp = reinterpret_cast<const float4*>(f + (size_t)b * D);
    const float4 a0 = fp[lane * 2 + 0];
    const float4 a1 = fp[lane * 2 + 1];
    const float fnb = fn[b];
    const int len = lengths[b];

    float opl[LMAX], ops[LMAX];
    int cs[LMAX];
    #pragma unroll
    for (int j = 0; j < LMAX; ++j) {
        const int c = pinds[(size_t)b * LMAX + j];
        cs[j] = c;
        const float4* wp = reinterpret_cast<const float4*>(w + (size_t)c * D);
        const float4 w0 = wp[lane * 2 + 0];
        const float4 w1 = wp[lane * 2 + 1];
        float d = a0.x*w0.x + a0.y*w0.y + a0.z*w0.z + a0.w*w0.w
                + a1.x*w1.x + a1.y*w1.y + a1.z*w1.z + a1.w*w1.w;
        d = wave_sum(d);
        const float cosv = d / fmaxf(fnb * wn[c], 1e-8f);
        const float sine = sqrtf(fminf(fmaxf(1.0f - cosv * cosv, 0.0f), 1.0f));
        float phi = cosv * COS_M - sine * SIN_M;
        phi = (cosv > TH) ? phi : (cosv - MM);
        opl[j] = S_SCALE * cosv;
        ops[j] = S_SCALE * phi;
    }

    // correct Z for unique positive classes (margin applied), then ragged CE
    float Zc = Zp;
    for (int j = 0; j < len; ++j) {
        bool dup = false;
        for (int jj = 0; jj < j; ++jj) dup = dup || (cs[jj] == cs[j]);
        if (!dup) Zc += expf(ops[j] - MFIX) - expf(opl[j] - MFIX);
    }
    const float lZ = logf(Zc);
    float acc = 0.0f;
    for (int j = 0; j < len; ++j) acc += (MFIX + lZ - ops[j]);
    const float Lf = (float)len;
    if (lane == 0) loss[b] = acc / (Lf * Lf);
}

__global__ void reduce_kernel(const float* __restrict__ loss, float* __restrict__ out) {
    __shared__ float sdata[256];
    const int t = threadIdx.x;
    float s = 0.0f;
    for (int i = t; i < B; i += 256) s += loss[i];
    sdata[t] = s;
    __syncthreads();
    for (int off = 128; off > 0; off >>= 1) {
        if (t < off) sdata[t] += sdata[t + off];
        __syncthreads();
    }
    if (t == 0) out[0] = sdata[0] * (1.0f / (float)B);
}

} // anonymous namespace

extern "C" void kernel_launch(void* const* d_in, const int* in_sizes, int n_in,
                              void* d_out, int out_size, void* d_ws, size_t ws_size,
                              hipStream_t stream) {
    const float* f   = (const float*)d_in[0];
    // d_in[1] = labels [B,C] — not needed (reconstructed from pinds/lengths)
    const float* w   = (const float*)d_in[2];
    const int* pinds = (const int*)d_in[3];
    const int* lens  = (const int*)d_in[4];
    float* out = (float*)d_out;

    char* ws = (char*)d_ws;
    size_t off = 0;
    auto alloc = [&](size_t bytes) { void* p = ws + off; off = (off + bytes + 255) & ~(size_t)255; return p; };

    float* wn   = (float*)alloc(C * 4);
    float* fn   = (float*)alloc(B * 4);
    float* pZ   = (float*)alloc((size_t)B * NPAN * 4);
    float* loss = (float*)alloc(B * 4);
    ulonglong2* Ap = (ulonglong2*)alloc((size_t)NROWT * KST * SLOTS * 16);
    ulonglong2* Bp = (ulonglong2*)alloc((size_t)NPAN  * KST * SLOTS * 16);

    pack_norm_kernel<<<dim3(NBLK_F + NBLK_W + NBLK_PAD), 256, 0, stream>>>(f, w, fn, wn, Ap, Bp);
    gemm_mfma_kernel<<<dim3(NWG), 256, 0, stream>>>(Ap, Bp, pZ);
    finalize_kernel<<<dim3(B), 64, 0, stream>>>(f, w, fn, wn, pinds, lens, pZ, loss);
    reduce_kernel<<<dim3(1), 256, 0, stream>>>(loss, out);
}